// Round 2
// baseline (136.035 us; speedup 1.0000x reference)
//
#include <hip/hip_runtime.h>
#include <hip/hip_fp16.h>

#define N_NODES 50000
#define E_EDGES 800000
#define NTILES  (E_EDGES / 16)   // 50000 exact

typedef __attribute__((ext_vector_type(8))) short short8;
typedef __attribute__((ext_vector_type(4))) float floatx4;

// float -> bf16 bits, round-to-nearest-even (used in prep only)
__device__ __forceinline__ short f2bf(float x) {
    union { float f; unsigned u; } v; v.f = x;
    unsigned r = v.u + 0x7FFFu + ((v.u >> 16) & 1u);
    return (short)(r >> 16);
}

// pack bf16x2 (RTZ) from two floats via v_perm_b32: 1 VALU per pair
__device__ __forceinline__ unsigned pk_bf16(float lo, float hi) {
    union { float f; unsigned u; } a, b; a.f = lo; b.f = hi;
    return __builtin_amdgcn_perm(b.u, a.u, 0x07060302u);
}

// Kernel A: per-node LayerNorm+ReLU -> h; out = bias + h @ root; zero agg row
__global__ __launch_bounds__(256) void node_kernel(
    const float* __restrict__ x, const float* __restrict__ gamma,
    const float* __restrict__ beta, const float* __restrict__ root,
    const float* __restrict__ bias, float* __restrict__ h,
    float* __restrict__ out, __half* __restrict__ agg)
{
    int n = blockIdx.x * blockDim.x + threadIdx.x;
    if (n >= N_NODES) return;
    const float* xr = x + n * 16;
    float xv[16];
    #pragma unroll
    for (int i = 0; i < 4; ++i) ((floatx4*)xv)[i] = ((const floatx4*)xr)[i];
    float mu = 0.f;
    #pragma unroll
    for (int i = 0; i < 16; ++i) mu += xv[i];
    mu *= (1.f / 16.f);
    float var = 0.f;
    #pragma unroll
    for (int i = 0; i < 16; ++i) { float d = xv[i] - mu; var += d * d; }
    var *= (1.f / 16.f);
    float rs = rsqrtf(var + 1e-5f);
    float hv[16];
    #pragma unroll
    for (int i = 0; i < 16; ++i) {
        float t = (xv[i] - mu) * rs * gamma[i] + beta[i];
        hv[i] = t > 0.f ? t : 0.f;
    }
    float* hr = h + n * 16;
    #pragma unroll
    for (int i = 0; i < 4; ++i) ((floatx4*)hr)[i] = ((floatx4*)hv)[i];

    // zero the f16 aggregation row for this node (32 B) before edge_kernel runs
    floatx4 z = {0.f, 0.f, 0.f, 0.f};
    floatx4* az = (floatx4*)(agg + (size_t)n * 16);
    az[0] = z; az[1] = z;

    float ov[16];
    #pragma unroll
    for (int o = 0; o < 16; ++o) ov[o] = bias[o];
    #pragma unroll
    for (int i = 0; i < 16; ++i) {
        float hi = hv[i];
        #pragma unroll
        for (int o = 0; o < 16; ++o) ov[o] += hi * root[i * 16 + o];
    }
    float* orow = out + n * 16;
    #pragma unroll
    for (int i = 0; i < 4; ++i) ((floatx4*)orow)[i] = ((floatx4*)ov)[i];
}

// Kernel W: W2t[m][k] = bf16(W2[k][m]), [16][160] bf16 = 5 KB.
__global__ __launch_bounds__(256) void prep_kernel(
    const float* __restrict__ w_edge, const float* __restrict__ b_edge,
    short* __restrict__ w2t)
{
    int t = blockIdx.x * blockDim.x + threadIdx.x;
    if (t >= 16 * 160) return;
    int m = t / 160, k = t % 160;
    float v = 0.f;
    if (k < 128)      v = w_edge[(k >> 4) * 256 + (k & 15) * 16 + m];
    else if (k < 144) v = b_edge[(k - 128) * 16 + m];
    w2t[m * 160 + k] = f2bf(v);
}

// Kernel B: ONE wave per tile of 16 edges. Epilogue: pk f16 atomics into agg —
// lanes pair across adjacent cols via shfl_xor(1); even lanes handle quad rows
// 0-1, odd lanes rows 2-3 -> 2 pk-atomic requests per lane (half the dword
// count of the fp32 version). unsafeAtomicAdd emits global_atomic_pk_add_f16.
__global__ __launch_bounds__(256) void edge_kernel(
    const int* __restrict__ eidx, const float* __restrict__ ea,
    const short* __restrict__ w2t, const float* __restrict__ h,
    __half* __restrict__ agg)
{
    const int lane = threadIdx.x & 63;
    const int wid  = threadIdx.x >> 6;
    const int m = lane & 15;   // edge-in-tile for A; output col for C/D and B
    const int q = lane >> 4;   // quad

    const int tile = blockIdx.x * 4 + wid;
    if (tile >= NTILES) return;

    const int e   = tile * 16 + m;
    const int src = eidx[e];
    const int dst = eidx[E_EDGES + e];

    const short* wp = w2t + m * 160 + 8 * q;
    short8 bfrag[5];
    #pragma unroll
    for (int c = 0; c < 5; ++c)
        bfrag[c] = *(const short8*)(wp + 32 * c);

    const float* er = ea + (size_t)e * 8;
    floatx4 ea0 = ((const floatx4*)er)[0];
    floatx4 ea1 = ((const floatx4*)er)[1];

    const float* hr = h + src * 16 + 8 * (q & 1);
    floatx4 h0 = ((const floatx4*)hr)[0];
    floatx4 h1 = ((const floatx4*)hr)[1];
    float hh[8] = {h0.x, h0.y, h0.z, h0.w, h1.x, h1.y, h1.z, h1.w};

    floatx4 acc = {0.f, 0.f, 0.f, 0.f};
    const int hi_t = q >> 1;
    #pragma unroll
    for (int c = 0; c < 4; ++c) {
        float t_even, t_odd;
        if (c == 0)      { t_even = ea0.x; t_odd = ea0.y; }
        else if (c == 1) { t_even = ea0.z; t_odd = ea0.w; }
        else if (c == 2) { t_even = ea1.x; t_odd = ea1.y; }
        else             { t_even = ea1.z; t_odd = ea1.w; }
        float s = hi_t ? t_odd : t_even;
        union { short8 s8; unsigned u[4]; } af;
        #pragma unroll
        for (int p = 0; p < 4; ++p)
            af.u[p] = pk_bf16(s * hh[2 * p], s * hh[2 * p + 1]);
        acc = __builtin_amdgcn_mfma_f32_16x16x32_bf16(af.s8, bfrag[c], acc, 0, 0, 0);
    }
    // chunk 4: z = h[i] for q<2, 0 otherwise (mask the packed words)
    {
        const unsigned msk = (q < 2) ? 0xFFFFFFFFu : 0u;
        union { short8 s8; unsigned u[4]; } af;
        #pragma unroll
        for (int p = 0; p < 4; ++p)
            af.u[p] = pk_bf16(hh[2 * p], hh[2 * p + 1]) & msk;
        acc = __builtin_amdgcn_mfma_f32_16x16x32_bf16(af.s8, bfrag[4], acc, 0, 0, 0);
    }

    // C/D layout: col = m, row = 4q + r (edge index in tile).
    // Pair columns (mlo, mlo+1) into one __half2 pk atomic.
    const int odd = m & 1;
    const int mlo = m & ~1;
    #pragma unroll
    for (int r = 0; r < 4; ++r) {
        float p  = __shfl_xor(acc[r], 1, 64);
        float lo = odd ? p : acc[r];
        float hi = odd ? acc[r] : p;
        __half2 v = __floats2half2_rn(lo, hi);
        int dr = __shfl(dst, 4 * q + r, 64);
        if ((r >> 1) == odd)   // even lanes: rows 0,1; odd lanes: rows 2,3
            unsafeAtomicAdd((__half2*)(agg + (size_t)dr * 16 + mlo), v);
    }
}

// Kernel M: out += float(agg)
__global__ __launch_bounds__(256) void merge_kernel(
    const __half* __restrict__ agg, float* __restrict__ out)
{
    int n = blockIdx.x * blockDim.x + threadIdx.x;
    if (n >= N_NODES) return;
    const __half2* ar = (const __half2*)(agg + (size_t)n * 16);
    float* orow = out + (size_t)n * 16;
    floatx4 o[4];
    #pragma unroll
    for (int i = 0; i < 4; ++i) o[i] = ((floatx4*)orow)[i];
    #pragma unroll
    for (int j = 0; j < 8; ++j) {
        float2 f = __half22float2(ar[j]);
        o[j / 2][(j & 1) * 2 + 0] += f.x;
        o[j / 2][(j & 1) * 2 + 1] += f.y;
    }
    #pragma unroll
    for (int i = 0; i < 4; ++i) ((floatx4*)orow)[i] = o[i];
}

extern "C" void kernel_launch(void* const* d_in, const int* in_sizes, int n_in,
                              void* d_out, int out_size, void* d_ws, size_t ws_size,
                              hipStream_t stream) {
    const float* x        = (const float*)d_in[0];
    const int*   eidx     = (const int*)d_in[1];
    const float* ea       = (const float*)d_in[2];
    const float* ln_gamma = (const float*)d_in[3];
    const float* ln_beta  = (const float*)d_in[4];
    const float* w_edge   = (const float*)d_in[5];
    const float* b_edge   = (const float*)d_in[6];
    const float* root     = (const float*)d_in[7];
    const float* bias     = (const float*)d_in[8];
    float* out = (float*)d_out;

    // workspace: h [N*16 f32 = 3.2 MB] | w2t [16*160 bf16 = 5 KB] | agg [N*16 f16 = 1.6 MB]
    char* ws = (char*)d_ws;
    float*  h   = (float*)ws;
    short*  w2t = (short*)(ws + (size_t)N_NODES * 16 * 4);
    __half* agg = (__half*)(ws + (size_t)N_NODES * 16 * 4 + 16 * 160 * 2);

    prep_kernel<<<10, 256, 0, stream>>>(w_edge, b_edge, w2t);
    node_kernel<<<(N_NODES + 255) / 256, 256, 0, stream>>>(
        x, ln_gamma, ln_beta, root, bias, h, out, agg);
    edge_kernel<<<(NTILES + 3) / 4, 256, 0, stream>>>(eidx, ea, w2t, h, agg);
    merge_kernel<<<(N_NODES + 255) / 256, 256, 0, stream>>>(agg, out);
}